// Round 18
// baseline (317.595 us; speedup 1.0000x reference)
//
#include <hip/hip_runtime.h>

#define V 80000
#define E 640000
#define D 128
#define NREL 500
#define HALF (E/2)
#define NGROUP 1000
#define EP (E + NGROUP * 32)
#define NBLK_D ((V + 1023) / 1024)
#define NREP 320
#define SLABLOG 11
#define SLAB 2048
#define NSLAB ((E + SLAB - 1) / SLAB)   // 313
#define MAXPART 5008

typedef __attribute__((ext_vector_type(8))) short s8v;
typedef __attribute__((ext_vector_type(4))) float f4v;
typedef __attribute__((ext_vector_type(4))) int i4v;
typedef __attribute__((ext_vector_type(4))) unsigned u4v;
typedef unsigned long long u64;

__device__ __forceinline__ unsigned short f2bf(float f) {
  unsigned u = __float_as_uint(f);
  return (unsigned short)((u + 0x7fffu + ((u >> 16) & 1u)) >> 16);
}
__device__ __forceinline__ unsigned cvtpk(float lo, float hi) {
  unsigned r;
  asm("v_cvt_pk_bf16_f32 %0, %1, %2" : "=v"(r) : "v"(lo), "v"(hi));
  return r;
}

__global__ void k_init(u64* packed, int* hist, uint4* edat) {
  int i = blockIdx.x * 256 + threadIdx.x;
  if (i < V) packed[i] = 0ull;
  if (i < NGROUP * NREP) hist[i] = 0;
  if (i < EP) { uint4 r; r.x = 0; r.y = 0xFFFFFFFFu; r.z = 0; r.w = 0; edat[i] = r; }
}

// fused prep: blocks [0,500)=rel/out1/rw/relb ; [500,628)=mltb ; [628,884)=wtb
__global__ void k_prep(const float* __restrict__ rel, const float* __restrict__ w_rel,
                       const float* __restrict__ attn_w, const float* __restrict__ loop_rel,
                       const float* __restrict__ loop_w, const float* __restrict__ in_w,
                       const float* __restrict__ out_w, float* __restrict__ out1,
                       float* __restrict__ rw, unsigned short* __restrict__ relb,
                       unsigned short* __restrict__ mltb, unsigned short* __restrict__ wtb) {
  int b = blockIdx.x, n = threadIdx.x;
  if (b < NREL) {
    __shared__ float rs[D];
    __shared__ float red[D];
    float rv = rel[b * D + n];
    rs[n] = rv;
    relb[b * D + n] = f2bf(rv);
    red[n] = rv * attn_w[D + n];
    __syncthreads();
    float acc = 0.f;
    #pragma unroll 8
    for (int j = 0; j < D; ++j) acc += rs[j] * w_rel[j * D + n];
    out1[b * D + n] = acc;
    if (n == 0) {
      float s = 0.f;
      for (int j = 0; j < D; ++j) s += red[j];
      rw[b] = s;
    }
  } else if (b < NREL + D) {
    int j = b - NREL;
    __shared__ float ls[2 * D];
    ls[n] = loop_rel[n]; ls[n + D] = loop_rel[n];
    __syncthreads();
    float acc = 0.f;
    #pragma unroll 8
    for (int k = 0; k < D; ++k) acc += ls[j + k] * loop_w[k * D + n];
    mltb[n * D + j] = f2bf(acc);
  } else {
    int bw = b - NREL - D;
    int h = bw >> 7, n2 = bw & 127;
    const float* W = h ? out_w : in_w;
    wtb[h * 16384 + n2 * D + n] = f2bf(W[n * D + n2]);
  }
}

// fused: x -> bf16 xb ; sxw/dxw projections; 16-lane subgroups, 4 rows/wave
__global__ void k_xbproj(const float* __restrict__ x, const float* __restrict__ attn_w,
                         uint4* __restrict__ xb4, float* __restrict__ sxw,
                         float* __restrict__ dxw) {
  int tid = threadIdx.x;
  int wid = tid >> 6, lane = tid & 63;
  int sub = lane >> 4, ln = lane & 15;
  float ws[8], wd[8];
  #pragma unroll
  for (int i = 0; i < 8; ++i) {
    ws[i] = attn_w[ln * 8 + i];
    wd[i] = attn_w[256 + ln * 8 + i];
  }
  for (int v = blockIdx.x * 16 + wid * 4 + sub; v < V; v += 2048 * 16) {
    f4v x0 = *(const f4v*)&x[(size_t)v * D + ln * 8];
    f4v x1 = *(const f4v*)&x[(size_t)v * D + ln * 8 + 4];
    float ps = 0.f, pd = 0.f;
    #pragma unroll
    for (int i = 0; i < 4; ++i) {
      ps += x0[i] * ws[i] + x1[i] * ws[4 + i];
      pd += x0[i] * wd[i] + x1[i] * wd[4 + i];
    }
    #pragma unroll
    for (int off = 1; off < 16; off <<= 1) {
      ps += __shfl_xor(ps, off);
      pd += __shfl_xor(pd, off);
    }
    if (ln == 0) { sxw[v] = ps; dxw[v] = pd; }
    uint4 qv;
    qv.x = (unsigned)f2bf(x0[0]) | ((unsigned)f2bf(x0[1]) << 16);
    qv.y = (unsigned)f2bf(x0[2]) | ((unsigned)f2bf(x0[3]) << 16);
    qv.z = (unsigned)f2bf(x1[0]) | ((unsigned)f2bf(x1[1]) << 16);
    qv.w = (unsigned)f2bf(x1[2]) | ((unsigned)f2bf(x1[3]) << 16);
    xb4[(size_t)v * 16 + ln] = qv;
  }
}

// MbT[g][n][j] = sum_k rel_t[(j+k)%128] * W_h[k][n]  via MFMA
__global__ __launch_bounds__(256) void k_mbt2(const unsigned short* __restrict__ relb,
    const unsigned short* __restrict__ wtb, unsigned short* __restrict__ mbt) {
  __shared__ unsigned short relp[256];
  __shared__ unsigned short Wl[D * D];
  int g = blockIdx.x, tid = threadIdx.x;
  int t = (g >= NREL) ? g - NREL : g;
  const unsigned short* wt = wtb + (g >= NREL ? 16384 : 0);
  relp[tid] = relb[t * D + (tid & 127)];
  #pragma unroll
  for (int i = 0; i < 8; ++i) {
    int idx = tid + i * 256;
    int n = idx >> 4, kc = idx & 15;
    *(uint4*)((char*)Wl + n * 256 + ((kc ^ (n & 7)) << 4)) = *(const uint4*)(wt + n * D + kc * 8);
  }
  __syncthreads();
  int wid = tid >> 6, ln = tid & 15, hi = (tid & 63) >> 4;
  s8v af[2][4];
  #pragma unroll
  for (int m = 0; m < 2; ++m) {
    int j = wid * 32 + m * 16 + ln;
    #pragma unroll
    for (int ks = 0; ks < 4; ++ks) {
      int o = j + ks * 32 + hi * 8;
      s8v a;
      #pragma unroll
      for (int i = 0; i < 8; ++i) a[i] = (short)relp[o + i];
      af[m][ks] = a;
    }
  }
  f4v acc[2][8];
  #pragma unroll
  for (int m = 0; m < 2; ++m)
    #pragma unroll
    for (int nn = 0; nn < 8; ++nn) acc[m][nn] = (f4v){0.f, 0.f, 0.f, 0.f};
  #pragma unroll
  for (int ks = 0; ks < 4; ++ks) {
    #pragma unroll
    for (int nn = 0; nn < 8; ++nn) {
      int n2 = nn * 16 + ln;
      int kc = (ks * 4 + hi) ^ (n2 & 7);
      s8v b = *(const s8v*)((const char*)Wl + n2 * 256 + (kc << 4));
      #pragma unroll
      for (int m = 0; m < 2; ++m)
        acc[m][nn] = __builtin_amdgcn_mfma_f32_16x16x32_bf16(af[m][ks], b, acc[m][nn], 0, 0, 0);
    }
  }
  size_t gb = (size_t)g * (D * D);
  #pragma unroll
  for (int m = 0; m < 2; ++m)
    #pragma unroll
    for (int nn = 0; nn < 8; ++nn) {
      int jb = wid * 32 + m * 16 + hi * 4;
      u64 pk = (u64)f2bf(acc[m][nn][0])
        | ((u64)f2bf(acc[m][nn][1]) << 16)
        | ((u64)f2bf(acc[m][nn][2]) << 32)
        | ((u64)f2bf(acc[m][nn][3]) << 48);
      *(u64*)&mbt[gb + (size_t)(nn * 16 + ln) * D + jb] = pk;
    }
}

// out0 init = (xb @ MloopT^T)/3 + bias  via MFMA
__global__ __launch_bounds__(256) void k_lgemm(const unsigned short* __restrict__ xb,
    const unsigned short* __restrict__ mltb, const float* __restrict__ bias,
    float* __restrict__ out0) {
  __shared__ unsigned short Wl[D * D];
  int tid = threadIdx.x;
  #pragma unroll
  for (int i = 0; i < 8; ++i) {
    int idx = tid + i * 256;
    int n = idx >> 4, kc = idx & 15;
    *(uint4*)((char*)Wl + n * 256 + ((kc ^ (n & 7)) << 4)) = *(const uint4*)(mltb + n * D + kc * 8);
  }
  __syncthreads();
  int wid = tid >> 6, ln = tid & 15, hi = (tid & 63) >> 4;
  int rbase = blockIdx.x * 128 + wid * 32;
  s8v af[2][4];
  #pragma unroll
  for (int m = 0; m < 2; ++m)
    #pragma unroll
    for (int ks = 0; ks < 4; ++ks)
      af[m][ks] = *(const s8v*)(xb + (size_t)(rbase + m * 16 + ln) * D + ks * 32 + hi * 8);
  f4v acc[2][8];
  #pragma unroll
  for (int m = 0; m < 2; ++m)
    #pragma unroll
    for (int nn = 0; nn < 8; ++nn) acc[m][nn] = (f4v){0.f, 0.f, 0.f, 0.f};
  #pragma unroll
  for (int ks = 0; ks < 4; ++ks) {
    #pragma unroll
    for (int nn = 0; nn < 8; ++nn) {
      int n2 = nn * 16 + ln;
      int kc = (ks * 4 + hi) ^ (n2 & 7);
      s8v b = *(const s8v*)((const char*)Wl + n2 * 256 + (kc << 4));
      #pragma unroll
      for (int m = 0; m < 2; ++m)
        acc[m][nn] = __builtin_amdgcn_mfma_f32_16x16x32_bf16(af[m][ks], b, acc[m][nn], 0, 0, 0);
    }
  }
  float bcol[8];
  #pragma unroll
  for (int nn = 0; nn < 8; ++nn) bcol[nn] = bias[nn * 16 + ln];
  #pragma unroll
  for (int m = 0; m < 2; ++m)
    #pragma unroll
    for (int nn = 0; nn < 8; ++nn)
      #pragma unroll
      for (int r = 0; r < 4; ++r)
        out0[(size_t)(rbase + m * 16 + hi * 4 + r) * D + nn * 16 + ln] =
            acc[m][nn][r] * (1.f / 3.f) + bcol[nn];
}

// per-edge phase A: one block per 2048-edge slab; LDS ranking for grank;
// one global u64 atomic/edge
__global__ __launch_bounds__(512) void k_edge(const int* __restrict__ src,
                       const int* __restrict__ dst,
                       const int* __restrict__ et, const float* __restrict__ sxw,
                       const float* __restrict__ dxw, const float* __restrict__ rw,
                       float* __restrict__ evals, u64* __restrict__ packed,
                       int* __restrict__ hist, unsigned short* __restrict__ drank,
                       unsigned short* __restrict__ grank) {
  __shared__ int lhist[NGROUP];
  int r = blockIdx.x, tid = threadIdx.x;
  for (int t = tid; t < NGROUP; t += 512) lhist[t] = 0;
  __syncthreads();
  #pragma unroll
  for (int c = 0; c < 4; ++c) {
    int i = r * SLAB + c * 512 + tid;
    if (i < E) {
      int d = dst[i];
      float ev = sxw[src[i]] + rw[et[i]] + dxw[d];
      ev = ev >= 0.f ? ev : 0.01f * ev;
      float xv = __expf(ev);
      evals[i] = xv;
      u64 inc = (1ull << 48) + (u64)(xv * 65536.f + 0.5f);
      u64 old = atomicAdd(&packed[d], inc);
      drank[i] = (unsigned short)(old >> 48);
      int g = et[i] + ((i >= HALF) ? NREL : 0);
      int gr = atomicAdd(&lhist[g], 1);
      grank[i] = (unsigned short)gr;
    }
  }
  __syncthreads();
  for (int t = tid; t < NGROUP; t += 512) hist[t * NREP + r] = lhist[t];
}

// one wave per group: wave-parallel row prefix of hist -> rowpref, cnt
__global__ void k_gmeta(const int* __restrict__ hist, int* __restrict__ cnt,
                        int* __restrict__ rowpref) {
  int wv = (blockIdx.x * 256 + threadIdx.x) >> 6;
  int lane = threadIdx.x & 63;
  if (wv >= NGROUP) return;
  int running = 0;
  #pragma unroll
  for (int c = 0; c < NREP / 64; ++c) {
    int r = c * 64 + lane;
    int v = hist[wv * NREP + r];
    int inc = v;
    #pragma unroll
    for (int off = 1; off < 64; off <<= 1) {
      int u = __shfl_up(inc, off);
      if (lane >= off) inc += u;
    }
    rowpref[wv * NREP + r] = running + inc - v;
    running += __shfl(inc, 63);
  }
  if (lane == 63) cnt[wv] = running;
}

// padded exclusive scan of cnt -> poffs (single block)
__global__ void k_scan(const int* __restrict__ cnt, int* __restrict__ poffs) {
  __shared__ int tmp[1024];
  int t = threadIdx.x;
  int c = (t < NGROUP) ? cnt[t] : 0;
  int pc = (c + 31) & ~31;
  tmp[t] = pc;
  __syncthreads();
  #pragma unroll
  for (int off = 1; off < 1024; off <<= 1) {
    int v = (t >= off) ? tmp[t - off] : 0;
    __syncthreads();
    tmp[t] += v;
    __syncthreads();
  }
  poffs[t] = tmp[t] - pc;
}

// decode packed -> esum/count + block scan
__global__ void k_dscan1(const u64* __restrict__ packed, float* __restrict__ esum,
                         int* __restrict__ dloc, int* __restrict__ dtot) {
  __shared__ int tmp[1024];
  int t = threadIdx.x;
  int i = blockIdx.x * 1024 + t;
  int v = 0;
  if (i < V) {
    u64 q = packed[i];
    esum[i] = (float)(q & 0xFFFFFFFFFFFFull) * (1.f / 65536.f);
    v = (int)(q >> 48);
  }
  tmp[t] = v;
  __syncthreads();
  #pragma unroll
  for (int off = 1; off < 1024; off <<= 1) {
    int u = (t >= off) ? tmp[t - off] : 0;
    __syncthreads();
    tmp[t] += u;
    __syncthreads();
  }
  if (i < V) dloc[i] = tmp[t] - v;
  if (t == 1023) dtot[blockIdx.x] = tmp[t];
}

// dscan3 with built-in 128-wide scan of dtot
__global__ void k_dscan3(const int* __restrict__ dloc, const int* __restrict__ dtot,
                         int* __restrict__ doffs) {
  __shared__ int sh[128];
  int t = threadIdx.x;
  if (t < 128) sh[t] = (t < NBLK_D) ? dtot[t] : 0;
  __syncthreads();
  #pragma unroll
  for (int off = 1; off < 128; off <<= 1) {
    int v = (t >= off && t < 128) ? sh[t - off] : 0;
    __syncthreads();
    if (t < 128) sh[t] += v;
    __syncthreads();
  }
  int bo = (blockIdx.x == 0) ? 0 : sh[blockIdx.x - 1];
  int i = blockIdx.x * 1024 + t;
  if (i < V) doffs[i] = dloc[i] + bo;
  if (i == 0) doffs[V] = E;
}

// atomic-free scatter: pos = poffs[g] + rowpref[g][slab] + grank
__global__ void k_scatter(const int* __restrict__ src, const int* __restrict__ dst,
                          const int* __restrict__ et, const float* __restrict__ ee,
                          const float* __restrict__ esum, const float* __restrict__ enorm,
                          const int* __restrict__ poffs, const int* __restrict__ rowpref,
                          const int* __restrict__ doffs,
                          const unsigned short* __restrict__ drank,
                          const unsigned short* __restrict__ grank,
                          uint4* __restrict__ edat) {
  int i = blockIdx.x * 256 + threadIdx.x;
  if (i >= E) return;
  int g = et[i] + ((i >= HALF) ? NREL : 0);
  int r = i >> SLABLOG;
  int pos = poffs[g] + rowpref[g * NREP + r] + (int)grank[i];
  int d = dst[i];
  uint4 rec;
  rec.x = (unsigned)src[i];
  rec.y = (unsigned)(doffs[d] + (int)drank[i]);
  rec.z = __float_as_uint(ee[i] / esum[d] * enorm[i] * (1.f / 3.f));
  rec.w = 0;
  edat[pos] = rec;
}

// grouped gather-GEMM; 2 blocks/group XCD-paired; nontemporal msgb stores
// (keep L2 for xb gathers); nt edat loads
__global__ __launch_bounds__(256) void k_msg3(const unsigned short* __restrict__ xb,
    const unsigned short* __restrict__ mbt, const int* __restrict__ cnt,
    const int* __restrict__ poffs, const uint4* __restrict__ edat,
    const int* __restrict__ doffs, int loNode, int hiNode,
    unsigned short* __restrict__ msgb) {
  __shared__ uint4 Blds4[(D * 272) / 16];
  unsigned char* Bldsb = (unsigned char*)Blds4;
  int b = blockIdx.x;
  int g = (b >> 4) * 8 + (b & 7);
  int half = (b >> 3) & 1;
  if (g >= NGROUP) return;
  int c = cnt[g];
  if (c == 0) return;
  int tid = threadIdx.x;
  const uint4* Mg = (const uint4*)(mbt + (size_t)g * (D * D));
  #pragma unroll
  for (int i = 0; i < 8; ++i) {
    int idx = tid + i * 256;
    int row = idx >> 4, col = (idx & 15) * 16;
    Blds4[(row * 272 + col) >> 4] = Mg[idx];
  }
  __syncthreads();
  int b1 = doffs[loNode];
  int b2 = doffs[hiNode];
  int wid = tid >> 6, ln = tid & 15, hi = (tid & 63) >> 4;
  int base0 = poffs[g];
  int nch = (c + 15) >> 4;
  int ch = half * 4 + wid;
  u4v recp = (u4v){0, 0, 0, 0};
  s8v afp[4];
  if (ch < nch) {
    recp = __builtin_nontemporal_load((const u4v*)(edat + base0 + ch * 16 + ln));
    const unsigned short* xr = xb + (size_t)recp[0] * D + hi * 8;
    #pragma unroll
    for (int ks = 0; ks < 4; ++ks) afp[ks] = *(const s8v*)(xr + ks * 32);
  }
  for (; ch < nch; ch += 8) {
    u4v recc = recp;
    int nc2 = ch + 8;
    if (nc2 < nch) recp = __builtin_nontemporal_load((const u4v*)(edat + base0 + nc2 * 16 + ln));
    s8v afc[4];
    #pragma unroll
    for (int ks = 0; ks < 4; ++ks) afc[ks] = afp[ks];
    f4v acc[8];
    #pragma unroll
    for (int n = 0; n < 8; ++n) acc[n] = (f4v){0.f, 0.f, 0.f, 0.f};
    #pragma unroll
    for (int ks = 0; ks < 4; ++ks) {
      #pragma unroll
      for (int n = 0; n < 8; ++n) {
        int row = n * 16 + ln;
        s8v bf = *(const s8v*)(Bldsb + row * 272 + ks * 64 + hi * 16);
        acc[n] = __builtin_amdgcn_mfma_f32_16x16x32_bf16(afc[ks], bf, acc[n], 0, 0, 0);
      }
    }
    if (nc2 < nch) {
      const unsigned short* xr = xb + (size_t)recp[0] * D + hi * 8;
      #pragma unroll
      for (int ks = 0; ks < 4; ++ks) afp[ks] = *(const s8v*)(xr + ks * 32);
    }
    f4v sum = (f4v){0.f, 0.f, 0.f, 0.f};
    #pragma unroll
    for (int n = 0; n < 8; ++n)
      #pragma unroll
      for (int j = 0; j < 4; ++j) {
        float e = __expf(acc[n][j]);
        acc[n][j] = e;
        sum[j] += e;
      }
    #pragma unroll
    for (int off = 1; off < 16; off <<= 1)
      #pragma unroll
      for (int j = 0; j < 4; ++j) sum[j] += __shfl_xor(sum[j], off);
    #pragma unroll
    for (int j = 0; j < 4; ++j) {
      int dpos = __shfl((int)recc[1], hi * 4 + j, 16);
      if (dpos >= b1 && dpos < b2) {
        float cf = __uint_as_float(__shfl((int)recc[2], hi * 4 + j, 16));
        size_t rowb = (size_t)(dpos - b1) * D;
        float s = cf / sum[j];
        u4v qv;
        qv[0] = cvtpk(acc[0][j] * s, acc[1][j] * s);
        qv[1] = cvtpk(acc[2][j] * s, acc[3][j] * s);
        qv[2] = cvtpk(acc[4][j] * s, acc[5][j] * s);
        qv[3] = cvtpk(acc[6][j] * s, acc[7][j] * s);
        __builtin_nontemporal_store(qv, (u4v*)&msgb[rowb + ln * 8]);
      }
    }
  }
}

// per-node segment sum (4 nodes/wave, nt 16B loads) + fused BN partials (no atomics)
__global__ void k_sum(const unsigned short* __restrict__ msgb, const int* __restrict__ doffs,
                      float* __restrict__ out0, float* __restrict__ part,
                      int loNode, int hiNode, int partBase) {
  __shared__ float shs[4][128];
  __shared__ float shq[4][128];
  int tid = threadIdx.x;
  int wid = tid >> 6, lane = tid & 63;
  int sub = lane >> 4, ln = lane & 15;
  int d = loNode + blockIdx.x * 16 + wid * 4 + sub;
  float v[8];
  #pragma unroll
  for (int n = 0; n < 8; ++n) v[n] = 0.f;
  if (d < hiNode) {
    int b1 = doffs[loNode];
    int s0 = doffs[d];
    int len = doffs[d + 1] - s0;
    const unsigned short* mp = msgb + (size_t)(s0 - b1) * D + ln * 8;
    float a[8];
    #pragma unroll
    for (int n = 0; n < 8; ++n) a[n] = 0.f;
    for (int r = 0; r < len; ++r) {
      u4v q = __builtin_nontemporal_load((const u4v*)(mp + (size_t)r * D));
      a[0] += __uint_as_float(q[0] << 16);
      a[1] += __uint_as_float(q[0] & 0xffff0000u);
      a[2] += __uint_as_float(q[1] << 16);
      a[3] += __uint_as_float(q[1] & 0xffff0000u);
      a[4] += __uint_as_float(q[2] << 16);
      a[5] += __uint_as_float(q[2] & 0xffff0000u);
      a[6] += __uint_as_float(q[3] << 16);
      a[7] += __uint_as_float(q[3] & 0xffff0000u);
    }
    // position ln*8+n holds col n*16+ln
    float* orow = out0 + (size_t)d * D + ln;
    #pragma unroll
    for (int n = 0; n < 8; ++n) {
      float t = orow[n * 16] + a[n];
      orow[n * 16] = t;
      v[n] = t;
    }
  }
  float s[8], q2[8];
  #pragma unroll
  for (int n = 0; n < 8; ++n) { s[n] = v[n]; q2[n] = v[n] * v[n]; }
  #pragma unroll
  for (int off = 16; off < 64; off <<= 1)
    #pragma unroll
    for (int n = 0; n < 8; ++n) {
      s[n] += __shfl_xor(s[n], off);
      q2[n] += __shfl_xor(q2[n], off);
    }
  if (sub == 0) {
    #pragma unroll
    for (int n = 0; n < 8; ++n) {
      shs[wid][n * 16 + ln] = s[n];
      shq[wid][n * 16 + ln] = q2[n];
    }
  }
  __syncthreads();
  if (wid == 0) {
    float* pb = part + (size_t)(partBase + blockIdx.x) * 256;
    for (int c = lane; c < 128; c += 64) {
      pb[c] = shs[0][c] + shs[1][c] + shs[2][c] + shs[3][c];
      pb[128 + c] = shq[0][c] + shq[1][c] + shq[2][c] + shq[3][c];
    }
  }
}

// BN reduce stage a
__global__ void k_bn2a(const float* __restrict__ part, float* __restrict__ part2,
                       int rows, int rpb) {
  int t = threadIdx.x, b = blockIdx.x;
  int r1 = (b + 1) * rpb; if (r1 > rows) r1 = rows;
  float s = 0.f;
  for (int r = b * rpb; r < r1; ++r) s += part[(size_t)r * 256 + t];
  part2[b * 256 + t] = s;
}

// BN reduce stage b: mean/rstd
__global__ void k_bn2b(const float* __restrict__ part2, float* __restrict__ mrs) {
  __shared__ float sh[256];
  int t = threadIdx.x;
  float s = 0.f;
  for (int b = 0; b < 100; ++b) s += part2[b * 256 + t];
  sh[t] = s;
  __syncthreads();
  if (t < 128) {
    float mean = sh[t] * (1.f / V);
    float var = sh[128 + t] * (1.f / V) - mean * mean;
    mrs[t] = mean;
    mrs[128 + t] = rsqrtf(var + 1e-5f);
  }
}

__global__ void k_bn_norm(float* __restrict__ out0, const float* __restrict__ mrs) {
  int i = blockIdx.x * 256 + threadIdx.x;
  if (i >= V * D) return;
  int c = i & 127;
  out0[i] = (out0[i] - mrs[c]) * mrs[128 + c];
}

extern "C" void kernel_launch(void* const* d_in, const int* in_sizes, int n_in,
                              void* d_out, int out_size, void* d_ws, size_t ws_size,
                              hipStream_t stream) {
  const float* x        = (const float*)d_in[0];
  const float* rel      = (const float*)d_in[4];
  const float* enorm    = (const float*)d_in[5];
  const float* in_w     = (const float*)d_in[6];
  const float* out_w    = (const float*)d_in[7];
  const float* loop_w   = (const float*)d_in[8];
  const float* w_rel    = (const float*)d_in[9];
  const float* loop_rel = (const float*)d_in[10];
  const float* attn_w   = (const float*)d_in[11];
  const float* bias     = (const float*)d_in[12];
  const int* src = (const int*)d_in[13];
  const int* dst = (const int*)d_in[14];
  const int* et  = (const int*)d_in[15];

  float* out0 = (float*)d_out;
  float* out1 = out0 + (size_t)V * D;

  float* base = (float*)d_ws;
  size_t off = 0;
  float* sxw = base + off;      off += V;
  float* dxw = base + off;      off += V;
  float* esum = base + off;     off += V;
  float* evals = base + off;    off += E;
  float* rw = base + off;       off += 512;
  float* part = base + off;     off += (size_t)MAXPART * 256;
  float* part2 = base + off;    off += 100 * 256;
  float* mrs = base + off;      off += 256;
  int* cnt = (int*)(base + off);   off += 1024;
  int* poffs = (int*)(base + off); off += 1024;
  int* hist = (int*)(base + off);     off += NGROUP * NREP;
  int* rowpref = (int*)(base + off);  off += NGROUP * NREP;
  u64* packed = (u64*)(base + off);   off += 2 * V;   // 8B aligned
  int* dloc = (int*)(base + off);  off += V;
  int* doffs = (int*)(base + off); off += V + 2;
  int* dtot = (int*)(base + off);  off += 128;
  unsigned short* drank = (unsigned short*)(base + off); off += E / 2;
  unsigned short* grank = (unsigned short*)(base + off); off += E / 2;
  uint4* edat = (uint4*)(base + off); off += (size_t)4 * EP;   // 16B records
  unsigned short* mltb = (unsigned short*)(base + off); off += D * D / 2;
  unsigned short* relb = (unsigned short*)(base + off); off += NREL * D / 2;
  unsigned short* wtb  = (unsigned short*)(base + off); off += 2 * D * D / 2;
  unsigned short* xb   = (unsigned short*)(base + off); off += (size_t)V * D / 2;
  unsigned short* mbt  = (unsigned short*)(base + off); off += (size_t)NGROUP * D * D / 2;
  unsigned short* msgb = (unsigned short*)(base + off);

  size_t availF = (ws_size / 4 > off) ? (ws_size / 4 - off) : 0;
  int ns = 1;
  if ((size_t)EP * (D / 2) > availF) {
    ns = 2;
    while (ns < 64 && (size_t)(E / ns + 16384) * (D / 2) > availF) ns *= 2;
  }

  k_init<<<(EP + 255) / 256, 256, 0, stream>>>(packed, hist, edat);
  k_prep<<<NREL + D + 256, 128, 0, stream>>>(rel, w_rel, attn_w, loop_rel, loop_w,
                                             in_w, out_w, out1, rw, relb, mltb, wtb);
  k_xbproj<<<2048, 256, 0, stream>>>(x, attn_w, (uint4*)xb, sxw, dxw);
  k_mbt2<<<NGROUP, 256, 0, stream>>>(relb, wtb, mbt);
  k_lgemm<<<V / 128, 256, 0, stream>>>(xb, mltb, bias, out0);
  k_edge<<<NSLAB, 512, 0, stream>>>(src, dst, et, sxw, dxw, rw,
                                    evals, packed, hist, drank, grank);
  k_gmeta<<<(NGROUP * 64 + 255) / 256, 256, 0, stream>>>(hist, cnt, rowpref);
  k_scan<<<1, 1024, 0, stream>>>(cnt, poffs);
  k_dscan1<<<NBLK_D, 1024, 0, stream>>>(packed, esum, dloc, dtot);
  k_dscan3<<<NBLK_D, 1024, 0, stream>>>(dloc, dtot, doffs);
  k_scatter<<<(E + 255) / 256, 256, 0, stream>>>(src, dst, et, evals, esum, enorm,
                                                 poffs, rowpref, doffs, drank, grank, edat);
  int Vs = V / ns;
  int partBase = 0;
  for (int s = 0; s < ns; ++s) {
    int lo = s * Vs, hi = (s == ns - 1) ? V : (s + 1) * Vs;
    int nb = (hi - lo + 15) / 16;
    k_msg3<<<NGROUP * 2, 256, 0, stream>>>(xb, mbt, cnt, poffs, edat,
                                           doffs, lo, hi, msgb);
    k_sum<<<nb, 256, 0, stream>>>(msgb, doffs, out0, part, lo, hi, partBase);
    partBase += nb;
  }
  int rpb = (partBase + 99) / 100;
  k_bn2a<<<100, 256, 0, stream>>>(part, part2, partBase, rpb);
  k_bn2b<<<1, 256, 0, stream>>>(part2, mrs);
  k_bn_norm<<<(V * D + 255) / 256, 256, 0, stream>>>(out0, mrs);
}

// Round 19
// 307.159 us; speedup vs baseline: 1.0340x; 1.0340x over previous
//
#include <hip/hip_runtime.h>

#define V 80000
#define E 640000
#define D 128
#define NREL 500
#define HALF (E/2)
#define NGROUP 1000
#define EP (E + NGROUP * 32)
#define NBLK_D ((V + 1023) / 1024)
#define NREP 320
#define SLABLOG 11
#define SLAB 2048
#define NSLAB ((E + SLAB - 1) / SLAB)   // 313
#define MAXPART 5008

typedef __attribute__((ext_vector_type(8))) short s8v;
typedef __attribute__((ext_vector_type(4))) float f4v;
typedef __attribute__((ext_vector_type(4))) int i4v;
typedef unsigned long long u64;

__device__ __forceinline__ unsigned short f2bf(float f) {
  unsigned u = __float_as_uint(f);
  return (unsigned short)((u + 0x7fffu + ((u >> 16) & 1u)) >> 16);
}
__device__ __forceinline__ unsigned cvtpk(float lo, float hi) {
  unsigned r;
  asm("v_cvt_pk_bf16_f32 %0, %1, %2" : "=v"(r) : "v"(lo), "v"(hi));
  return r;
}

__global__ void k_init(u64* packed, int* hist, uint4* edat) {
  int i = blockIdx.x * 256 + threadIdx.x;
  if (i < V) packed[i] = 0ull;
  if (i < NGROUP * NREP) hist[i] = 0;
  if (i < EP) { uint4 r; r.x = 0; r.y = 0xFFFFFFFFu; r.z = 0; r.w = 0; edat[i] = r; }
}

// fused prep: blocks [0,500)=rel/out1/rw/relb ; [500,628)=mltb ; [628,884)=wtb
__global__ void k_prep(const float* __restrict__ rel, const float* __restrict__ w_rel,
                       const float* __restrict__ attn_w, const float* __restrict__ loop_rel,
                       const float* __restrict__ loop_w, const float* __restrict__ in_w,
                       const float* __restrict__ out_w, float* __restrict__ out1,
                       float* __restrict__ rw, unsigned short* __restrict__ relb,
                       unsigned short* __restrict__ mltb, unsigned short* __restrict__ wtb) {
  int b = blockIdx.x, n = threadIdx.x;
  if (b < NREL) {
    __shared__ float rs[D];
    __shared__ float red[D];
    float rv = rel[b * D + n];
    rs[n] = rv;
    relb[b * D + n] = f2bf(rv);
    red[n] = rv * attn_w[D + n];
    __syncthreads();
    float acc = 0.f;
    #pragma unroll 8
    for (int j = 0; j < D; ++j) acc += rs[j] * w_rel[j * D + n];
    out1[b * D + n] = acc;
    if (n == 0) {
      float s = 0.f;
      for (int j = 0; j < D; ++j) s += red[j];
      rw[b] = s;
    }
  } else if (b < NREL + D) {
    int j = b - NREL;
    __shared__ float ls[2 * D];
    ls[n] = loop_rel[n]; ls[n + D] = loop_rel[n];
    __syncthreads();
    float acc = 0.f;
    #pragma unroll 8
    for (int k = 0; k < D; ++k) acc += ls[j + k] * loop_w[k * D + n];
    mltb[n * D + j] = f2bf(acc);
  } else {
    int bw = b - NREL - D;
    int h = bw >> 7, n2 = bw & 127;
    const float* W = h ? out_w : in_w;
    wtb[h * 16384 + n2 * D + n] = f2bf(W[n * D + n2]);
  }
}

// fused: x -> bf16 xb ; sxw/dxw projections; 16-lane subgroups, 4 rows/wave
__global__ void k_xbproj(const float* __restrict__ x, const float* __restrict__ attn_w,
                         uint4* __restrict__ xb4, float* __restrict__ sxw,
                         float* __restrict__ dxw) {
  int tid = threadIdx.x;
  int wid = tid >> 6, lane = tid & 63;
  int sub = lane >> 4, ln = lane & 15;
  float ws[8], wd[8];
  #pragma unroll
  for (int i = 0; i < 8; ++i) {
    ws[i] = attn_w[ln * 8 + i];
    wd[i] = attn_w[256 + ln * 8 + i];
  }
  for (int v = blockIdx.x * 16 + wid * 4 + sub; v < V; v += 2048 * 16) {
    f4v x0 = *(const f4v*)&x[(size_t)v * D + ln * 8];
    f4v x1 = *(const f4v*)&x[(size_t)v * D + ln * 8 + 4];
    float ps = 0.f, pd = 0.f;
    #pragma unroll
    for (int i = 0; i < 4; ++i) {
      ps += x0[i] * ws[i] + x1[i] * ws[4 + i];
      pd += x0[i] * wd[i] + x1[i] * wd[4 + i];
    }
    #pragma unroll
    for (int off = 1; off < 16; off <<= 1) {
      ps += __shfl_xor(ps, off);
      pd += __shfl_xor(pd, off);
    }
    if (ln == 0) { sxw[v] = ps; dxw[v] = pd; }
    uint4 qv;
    qv.x = (unsigned)f2bf(x0[0]) | ((unsigned)f2bf(x0[1]) << 16);
    qv.y = (unsigned)f2bf(x0[2]) | ((unsigned)f2bf(x0[3]) << 16);
    qv.z = (unsigned)f2bf(x1[0]) | ((unsigned)f2bf(x1[1]) << 16);
    qv.w = (unsigned)f2bf(x1[2]) | ((unsigned)f2bf(x1[3]) << 16);
    xb4[(size_t)v * 16 + ln] = qv;
  }
}

// MbT[g][n][j] = sum_k rel_t[(j+k)%128] * W_h[k][n]  via MFMA
__global__ __launch_bounds__(256) void k_mbt2(const unsigned short* __restrict__ relb,
    const unsigned short* __restrict__ wtb, unsigned short* __restrict__ mbt) {
  __shared__ unsigned short relp[256];
  __shared__ unsigned short Wl[D * D];
  int g = blockIdx.x, tid = threadIdx.x;
  int t = (g >= NREL) ? g - NREL : g;
  const unsigned short* wt = wtb + (g >= NREL ? 16384 : 0);
  relp[tid] = relb[t * D + (tid & 127)];
  #pragma unroll
  for (int i = 0; i < 8; ++i) {
    int idx = tid + i * 256;
    int n = idx >> 4, kc = idx & 15;
    *(uint4*)((char*)Wl + n * 256 + ((kc ^ (n & 7)) << 4)) = *(const uint4*)(wt + n * D + kc * 8);
  }
  __syncthreads();
  int wid = tid >> 6, ln = tid & 15, hi = (tid & 63) >> 4;
  s8v af[2][4];
  #pragma unroll
  for (int m = 0; m < 2; ++m) {
    int j = wid * 32 + m * 16 + ln;
    #pragma unroll
    for (int ks = 0; ks < 4; ++ks) {
      int o = j + ks * 32 + hi * 8;
      s8v a;
      #pragma unroll
      for (int i = 0; i < 8; ++i) a[i] = (short)relp[o + i];
      af[m][ks] = a;
    }
  }
  f4v acc[2][8];
  #pragma unroll
  for (int m = 0; m < 2; ++m)
    #pragma unroll
    for (int nn = 0; nn < 8; ++nn) acc[m][nn] = (f4v){0.f, 0.f, 0.f, 0.f};
  #pragma unroll
  for (int ks = 0; ks < 4; ++ks) {
    #pragma unroll
    for (int nn = 0; nn < 8; ++nn) {
      int n2 = nn * 16 + ln;
      int kc = (ks * 4 + hi) ^ (n2 & 7);
      s8v b = *(const s8v*)((const char*)Wl + n2 * 256 + (kc << 4));
      #pragma unroll
      for (int m = 0; m < 2; ++m)
        acc[m][nn] = __builtin_amdgcn_mfma_f32_16x16x32_bf16(af[m][ks], b, acc[m][nn], 0, 0, 0);
    }
  }
  size_t gb = (size_t)g * (D * D);
  #pragma unroll
  for (int m = 0; m < 2; ++m)
    #pragma unroll
    for (int nn = 0; nn < 8; ++nn) {
      int jb = wid * 32 + m * 16 + hi * 4;
      u64 pk = (u64)f2bf(acc[m][nn][0])
        | ((u64)f2bf(acc[m][nn][1]) << 16)
        | ((u64)f2bf(acc[m][nn][2]) << 32)
        | ((u64)f2bf(acc[m][nn][3]) << 48);
      *(u64*)&mbt[gb + (size_t)(nn * 16 + ln) * D + jb] = pk;
    }
}

// out0 init = (xb @ MloopT^T)/3 + bias  via MFMA
__global__ __launch_bounds__(256) void k_lgemm(const unsigned short* __restrict__ xb,
    const unsigned short* __restrict__ mltb, const float* __restrict__ bias,
    float* __restrict__ out0) {
  __shared__ unsigned short Wl[D * D];
  int tid = threadIdx.x;
  #pragma unroll
  for (int i = 0; i < 8; ++i) {
    int idx = tid + i * 256;
    int n = idx >> 4, kc = idx & 15;
    *(uint4*)((char*)Wl + n * 256 + ((kc ^ (n & 7)) << 4)) = *(const uint4*)(mltb + n * D + kc * 8);
  }
  __syncthreads();
  int wid = tid >> 6, ln = tid & 15, hi = (tid & 63) >> 4;
  int rbase = blockIdx.x * 128 + wid * 32;
  s8v af[2][4];
  #pragma unroll
  for (int m = 0; m < 2; ++m)
    #pragma unroll
    for (int ks = 0; ks < 4; ++ks)
      af[m][ks] = *(const s8v*)(xb + (size_t)(rbase + m * 16 + ln) * D + ks * 32 + hi * 8);
  f4v acc[2][8];
  #pragma unroll
  for (int m = 0; m < 2; ++m)
    #pragma unroll
    for (int nn = 0; nn < 8; ++nn) acc[m][nn] = (f4v){0.f, 0.f, 0.f, 0.f};
  #pragma unroll
  for (int ks = 0; ks < 4; ++ks) {
    #pragma unroll
    for (int nn = 0; nn < 8; ++nn) {
      int n2 = nn * 16 + ln;
      int kc = (ks * 4 + hi) ^ (n2 & 7);
      s8v b = *(const s8v*)((const char*)Wl + n2 * 256 + (kc << 4));
      #pragma unroll
      for (int m = 0; m < 2; ++m)
        acc[m][nn] = __builtin_amdgcn_mfma_f32_16x16x32_bf16(af[m][ks], b, acc[m][nn], 0, 0, 0);
    }
  }
  float bcol[8];
  #pragma unroll
  for (int nn = 0; nn < 8; ++nn) bcol[nn] = bias[nn * 16 + ln];
  #pragma unroll
  for (int m = 0; m < 2; ++m)
    #pragma unroll
    for (int nn = 0; nn < 8; ++nn)
      #pragma unroll
      for (int r = 0; r < 4; ++r)
        out0[(size_t)(rbase + m * 16 + hi * 4 + r) * D + nn * 16 + ln] =
            acc[m][nn][r] * (1.f / 3.f) + bcol[nn];
}

// per-edge phase A: one block per 2048-edge slab; LDS ranking for grank;
// one global u64 atomic/edge
__global__ __launch_bounds__(512) void k_edge(const int* __restrict__ src,
                       const int* __restrict__ dst,
                       const int* __restrict__ et, const float* __restrict__ sxw,
                       const float* __restrict__ dxw, const float* __restrict__ rw,
                       float* __restrict__ evals, u64* __restrict__ packed,
                       int* __restrict__ hist, unsigned short* __restrict__ drank,
                       unsigned short* __restrict__ grank) {
  __shared__ int lhist[NGROUP];
  int r = blockIdx.x, tid = threadIdx.x;
  for (int t = tid; t < NGROUP; t += 512) lhist[t] = 0;
  __syncthreads();
  #pragma unroll
  for (int c = 0; c < 4; ++c) {
    int i = r * SLAB + c * 512 + tid;
    if (i < E) {
      int d = dst[i];
      float ev = sxw[src[i]] + rw[et[i]] + dxw[d];
      ev = ev >= 0.f ? ev : 0.01f * ev;
      float xv = __expf(ev);
      evals[i] = xv;
      u64 inc = (1ull << 48) + (u64)(xv * 65536.f + 0.5f);
      u64 old = atomicAdd(&packed[d], inc);
      drank[i] = (unsigned short)(old >> 48);
      int g = et[i] + ((i >= HALF) ? NREL : 0);
      int gr = atomicAdd(&lhist[g], 1);
      grank[i] = (unsigned short)gr;
    }
  }
  __syncthreads();
  for (int t = tid; t < NGROUP; t += 512) hist[t * NREP + r] = lhist[t];
}

// one wave per group: wave-parallel row prefix of hist -> rowpref, cnt
__global__ void k_gmeta(const int* __restrict__ hist, int* __restrict__ cnt,
                        int* __restrict__ rowpref) {
  int wv = (blockIdx.x * 256 + threadIdx.x) >> 6;
  int lane = threadIdx.x & 63;
  if (wv >= NGROUP) return;
  int running = 0;
  #pragma unroll
  for (int c = 0; c < NREP / 64; ++c) {
    int r = c * 64 + lane;
    int v = hist[wv * NREP + r];
    int inc = v;
    #pragma unroll
    for (int off = 1; off < 64; off <<= 1) {
      int u = __shfl_up(inc, off);
      if (lane >= off) inc += u;
    }
    rowpref[wv * NREP + r] = running + inc - v;
    running += __shfl(inc, 63);
  }
  if (lane == 63) cnt[wv] = running;
}

// padded exclusive scan of cnt -> poffs (single block)
__global__ void k_scan(const int* __restrict__ cnt, int* __restrict__ poffs) {
  __shared__ int tmp[1024];
  int t = threadIdx.x;
  int c = (t < NGROUP) ? cnt[t] : 0;
  int pc = (c + 31) & ~31;
  tmp[t] = pc;
  __syncthreads();
  #pragma unroll
  for (int off = 1; off < 1024; off <<= 1) {
    int v = (t >= off) ? tmp[t - off] : 0;
    __syncthreads();
    tmp[t] += v;
    __syncthreads();
  }
  poffs[t] = tmp[t] - pc;
}

// decode packed -> esum/count + block scan
__global__ void k_dscan1(const u64* __restrict__ packed, float* __restrict__ esum,
                         int* __restrict__ dloc, int* __restrict__ dtot) {
  __shared__ int tmp[1024];
  int t = threadIdx.x;
  int i = blockIdx.x * 1024 + t;
  int v = 0;
  if (i < V) {
    u64 q = packed[i];
    esum[i] = (float)(q & 0xFFFFFFFFFFFFull) * (1.f / 65536.f);
    v = (int)(q >> 48);
  }
  tmp[t] = v;
  __syncthreads();
  #pragma unroll
  for (int off = 1; off < 1024; off <<= 1) {
    int u = (t >= off) ? tmp[t - off] : 0;
    __syncthreads();
    tmp[t] += u;
    __syncthreads();
  }
  if (i < V) dloc[i] = tmp[t] - v;
  if (t == 1023) dtot[blockIdx.x] = tmp[t];
}

// dscan3 with built-in 128-wide scan of dtot
__global__ void k_dscan3(const int* __restrict__ dloc, const int* __restrict__ dtot,
                         int* __restrict__ doffs) {
  __shared__ int sh[128];
  int t = threadIdx.x;
  if (t < 128) sh[t] = (t < NBLK_D) ? dtot[t] : 0;
  __syncthreads();
  #pragma unroll
  for (int off = 1; off < 128; off <<= 1) {
    int v = (t >= off && t < 128) ? sh[t - off] : 0;
    __syncthreads();
    if (t < 128) sh[t] += v;
    __syncthreads();
  }
  int bo = (blockIdx.x == 0) ? 0 : sh[blockIdx.x - 1];
  int i = blockIdx.x * 1024 + t;
  if (i < V) doffs[i] = dloc[i] + bo;
  if (i == 0) doffs[V] = E;
}

// atomic-free scatter: pos = poffs[g] + rowpref[g][slab] + grank
__global__ void k_scatter(const int* __restrict__ src, const int* __restrict__ dst,
                          const int* __restrict__ et, const float* __restrict__ ee,
                          const float* __restrict__ esum, const float* __restrict__ enorm,
                          const int* __restrict__ poffs, const int* __restrict__ rowpref,
                          const int* __restrict__ doffs,
                          const unsigned short* __restrict__ drank,
                          const unsigned short* __restrict__ grank,
                          uint4* __restrict__ edat) {
  int i = blockIdx.x * 256 + threadIdx.x;
  if (i >= E) return;
  int g = et[i] + ((i >= HALF) ? NREL : 0);
  int r = i >> SLABLOG;
  int pos = poffs[g] + rowpref[g * NREP + r] + (int)grank[i];
  int d = dst[i];
  uint4 rec;
  rec.x = (unsigned)src[i];
  rec.y = (unsigned)(doffs[d] + (int)drank[i]);
  rec.z = __float_as_uint(ee[i] / esum[d] * enorm[i] * (1.f / 3.f));
  rec.w = 0;
  edat[pos] = rec;
}

// grouped gather-GEMM; 2 blocks/group with XCD-pair-aware mapping so both
// halves of a group stage mbt on the SAME XCD's L2; AoS records; cvt_pk stores
__global__ __launch_bounds__(256) void k_msg3(const unsigned short* __restrict__ xb,
    const unsigned short* __restrict__ mbt, const int* __restrict__ cnt,
    const int* __restrict__ poffs, const uint4* __restrict__ edat,
    const int* __restrict__ doffs, int loNode, int hiNode,
    unsigned short* __restrict__ msgb) {
  __shared__ uint4 Blds4[(D * 272) / 16];
  unsigned char* Bldsb = (unsigned char*)Blds4;
  // blocks b and b+8 share an XCD under round-robin dispatch -> same group
  int b = blockIdx.x;
  int g = (b >> 4) * 8 + (b & 7);
  int half = (b >> 3) & 1;
  if (g >= NGROUP) return;
  int c = cnt[g];
  if (c == 0) return;
  int tid = threadIdx.x;
  const uint4* Mg = (const uint4*)(mbt + (size_t)g * (D * D));
  #pragma unroll
  for (int i = 0; i < 8; ++i) {
    int idx = tid + i * 256;
    int row = idx >> 4, col = (idx & 15) * 16;
    Blds4[(row * 272 + col) >> 4] = Mg[idx];
  }
  __syncthreads();
  int b1 = doffs[loNode];
  int b2 = doffs[hiNode];
  int wid = tid >> 6, ln = tid & 15, hi = (tid & 63) >> 4;
  int base0 = poffs[g];
  int nch = (c + 15) >> 4;
  int ch = half * 4 + wid;
  uint4 recp;
  s8v afp[4];
  if (ch < nch) {
    recp = edat[base0 + ch * 16 + ln];
    const unsigned short* xr = xb + (size_t)recp.x * D + hi * 8;
    #pragma unroll
    for (int ks = 0; ks < 4; ++ks) afp[ks] = *(const s8v*)(xr + ks * 32);
  }
  for (; ch < nch; ch += 8) {
    uint4 recc = recp;
    int nc2 = ch + 8;
    if (nc2 < nch) recp = edat[base0 + nc2 * 16 + ln];
    s8v afc[4];
    #pragma unroll
    for (int ks = 0; ks < 4; ++ks) afc[ks] = afp[ks];
    f4v acc[8];
    #pragma unroll
    for (int n = 0; n < 8; ++n) acc[n] = (f4v){0.f, 0.f, 0.f, 0.f};
    #pragma unroll
    for (int ks = 0; ks < 4; ++ks) {
      #pragma unroll
      for (int n = 0; n < 8; ++n) {
        int row = n * 16 + ln;
        s8v bf = *(const s8v*)(Bldsb + row * 272 + ks * 64 + hi * 16);
        acc[n] = __builtin_amdgcn_mfma_f32_16x16x32_bf16(afc[ks], bf, acc[n], 0, 0, 0);
      }
    }
    if (nc2 < nch) {
      const unsigned short* xr = xb + (size_t)recp.x * D + hi * 8;
      #pragma unroll
      for (int ks = 0; ks < 4; ++ks) afp[ks] = *(const s8v*)(xr + ks * 32);
    }
    f4v sum = (f4v){0.f, 0.f, 0.f, 0.f};
    #pragma unroll
    for (int n = 0; n < 8; ++n)
      #pragma unroll
      for (int j = 0; j < 4; ++j) {
        float e = __expf(acc[n][j]);
        acc[n][j] = e;
        sum[j] += e;
      }
    #pragma unroll
    for (int off = 1; off < 16; off <<= 1)
      #pragma unroll
      for (int j = 0; j < 4; ++j) sum[j] += __shfl_xor(sum[j], off);
    #pragma unroll
    for (int j = 0; j < 4; ++j) {
      int dpos = __shfl((int)recc.y, hi * 4 + j, 16);
      if (dpos >= b1 && dpos < b2) {
        float cf = __uint_as_float(__shfl((int)recc.z, hi * 4 + j, 16));
        size_t rowb = (size_t)(dpos - b1) * D;
        float s = cf / sum[j];
        uint4 qv;
        qv.x = cvtpk(acc[0][j] * s, acc[1][j] * s);
        qv.y = cvtpk(acc[2][j] * s, acc[3][j] * s);
        qv.z = cvtpk(acc[4][j] * s, acc[5][j] * s);
        qv.w = cvtpk(acc[6][j] * s, acc[7][j] * s);
        *(uint4*)&msgb[rowb + ln * 8] = qv;
      }
    }
  }
}

// per-node segment sum (4 nodes/wave, 16B loads) + fused BN partials
// (shfl + plain-LDS + plain-global stores: ZERO atomics)
__global__ void k_sum(const unsigned short* __restrict__ msgb, const int* __restrict__ doffs,
                      float* __restrict__ out0, float* __restrict__ part,
                      int loNode, int hiNode, int partBase) {
  __shared__ float shs[4][128];
  __shared__ float shq[4][128];
  int tid = threadIdx.x;
  int wid = tid >> 6, lane = tid & 63;
  int sub = lane >> 4, ln = lane & 15;
  int d = loNode + blockIdx.x * 16 + wid * 4 + sub;
  float v[8];
  #pragma unroll
  for (int n = 0; n < 8; ++n) v[n] = 0.f;
  if (d < hiNode) {
    int b1 = doffs[loNode];
    int s0 = doffs[d];
    int len = doffs[d + 1] - s0;
    const unsigned short* mp = msgb + (size_t)(s0 - b1) * D + ln * 8;
    float a[8];
    #pragma unroll
    for (int n = 0; n < 8; ++n) a[n] = 0.f;
    for (int r = 0; r < len; ++r) {
      uint4 q = *(const uint4*)(mp + (size_t)r * D);
      a[0] += __uint_as_float(q.x << 16);
      a[1] += __uint_as_float(q.x & 0xffff0000u);
      a[2] += __uint_as_float(q.y << 16);
      a[3] += __uint_as_float(q.y & 0xffff0000u);
      a[4] += __uint_as_float(q.z << 16);
      a[5] += __uint_as_float(q.z & 0xffff0000u);
      a[6] += __uint_as_float(q.w << 16);
      a[7] += __uint_as_float(q.w & 0xffff0000u);
    }
    // position ln*8+n holds col n*16+ln
    float* orow = out0 + (size_t)d * D + ln;
    #pragma unroll
    for (int n = 0; n < 8; ++n) {
      float t = orow[n * 16] + a[n];
      orow[n * 16] = t;
      v[n] = t;
    }
  }
  float s[8], q2[8];
  #pragma unroll
  for (int n = 0; n < 8; ++n) { s[n] = v[n]; q2[n] = v[n] * v[n]; }
  #pragma unroll
  for (int off = 16; off < 64; off <<= 1)
    #pragma unroll
    for (int n = 0; n < 8; ++n) {
      s[n] += __shfl_xor(s[n], off);
      q2[n] += __shfl_xor(q2[n], off);
    }
  if (sub == 0) {
    #pragma unroll
    for (int n = 0; n < 8; ++n) {
      shs[wid][n * 16 + ln] = s[n];
      shq[wid][n * 16 + ln] = q2[n];
    }
  }
  __syncthreads();
  if (wid == 0) {
    float* pb = part + (size_t)(partBase + blockIdx.x) * 256;
    for (int c = lane; c < 128; c += 64) {
      pb[c] = shs[0][c] + shs[1][c] + shs[2][c] + shs[3][c];
      pb[128 + c] = shq[0][c] + shq[1][c] + shq[2][c] + shq[3][c];
    }
  }
}

// BN reduce stage a
__global__ void k_bn2a(const float* __restrict__ part, float* __restrict__ part2,
                       int rows, int rpb) {
  int t = threadIdx.x, b = blockIdx.x;
  int r1 = (b + 1) * rpb; if (r1 > rows) r1 = rows;
  float s = 0.f;
  for (int r = b * rpb; r < r1; ++r) s += part[(size_t)r * 256 + t];
  part2[b * 256 + t] = s;
}

// BN reduce stage b: mean/rstd
__global__ void k_bn2b(const float* __restrict__ part2, float* __restrict__ mrs) {
  __shared__ float sh[256];
  int t = threadIdx.x;
  float s = 0.f;
  for (int b = 0; b < 100; ++b) s += part2[b * 256 + t];
  sh[t] = s;
  __syncthreads();
  if (t < 128) {
    float mean = sh[t] * (1.f / V);
    float var = sh[128 + t] * (1.f / V) - mean * mean;
    mrs[t] = mean;
    mrs[128 + t] = rsqrtf(var + 1e-5f);
  }
}

__global__ void k_bn_norm(float* __restrict__ out0, const float* __restrict__ mrs) {
  int i = blockIdx.x * 256 + threadIdx.x;
  if (i >= V * D) return;
  int c = i & 127;
  out0[i] = (out0[i] - mrs[c]) * mrs[128 + c];
}

extern "C" void kernel_launch(void* const* d_in, const int* in_sizes, int n_in,
                              void* d_out, int out_size, void* d_ws, size_t ws_size,
                              hipStream_t stream) {
  const float* x        = (const float*)d_in[0];
  const float* rel      = (const float*)d_in[4];
  const float* enorm    = (const float*)d_in[5];
  const float* in_w     = (const float*)d_in[6];
  const float* out_w    = (const float*)d_in[7];
  const float* loop_w   = (const float*)d_in[8];
  const float* w_rel    = (const float*)d_in[9];
  const float* loop_rel = (const float*)d_in[10];
  const float* attn_w   = (const float*)d_in[11];
  const float* bias     = (const float*)d_in[12];
  const int* src = (const int*)d_in[13];
  const int* dst = (const int*)d_in[14];
  const int* et  = (const int*)d_in[15];

  float* out0 = (float*)d_out;
  float* out1 = out0 + (size_t)V * D;

  float* base = (float*)d_ws;
  size_t off = 0;
  float* sxw = base + off;      off += V;
  float* dxw = base + off;      off += V;
  float* esum = base + off;     off += V;
  float* evals = base + off;    off += E;
  float* rw = base + off;       off += 512;
  float* part = base + off;     off += (size_t)MAXPART * 256;
  float* part2 = base + off;    off += 100 * 256;
  float* mrs = base + off;      off += 256;
  int* cnt = (int*)(base + off);   off += 1024;
  int* poffs = (int*)(base + off); off += 1024;
  int* hist = (int*)(base + off);     off += NGROUP * NREP;
  int* rowpref = (int*)(base + off);  off += NGROUP * NREP;
  u64* packed = (u64*)(base + off);   off += 2 * V;   // 8B aligned
  int* dloc = (int*)(base + off);  off += V;
  int* doffs = (int*)(base + off); off += V + 2;
  int* dtot = (int*)(base + off);  off += 128;
  unsigned short* drank = (unsigned short*)(base + off); off += E / 2;
  unsigned short* grank = (unsigned short*)(base + off); off += E / 2;
  uint4* edat = (uint4*)(base + off); off += (size_t)4 * EP;   // 16B records
  unsigned short* mltb = (unsigned short*)(base + off); off += D * D / 2;
  unsigned short* relb = (unsigned short*)(base + off); off += NREL * D / 2;
  unsigned short* wtb  = (unsigned short*)(base + off); off += 2 * D * D / 2;
  unsigned short* xb   = (unsigned short*)(base + off); off += (size_t)V * D / 2;
  unsigned short* mbt  = (unsigned short*)(base + off); off += (size_t)NGROUP * D * D / 2;
  unsigned short* msgb = (unsigned short*)(base + off);

  size_t availF = (ws_size / 4 > off) ? (ws_size / 4 - off) : 0;
  int ns = 1;
  if ((size_t)EP * (D / 2) > availF) {
    ns = 2;
    while (ns < 64 && (size_t)(E / ns + 16384) * (D / 2) > availF) ns *= 2;
  }

  k_init<<<(EP + 255) / 256, 256, 0, stream>>>(packed, hist, edat);
  k_prep<<<NREL + D + 256, 128, 0, stream>>>(rel, w_rel, attn_w, loop_rel, loop_w,
                                             in_w, out_w, out1, rw, relb, mltb, wtb);
  k_xbproj<<<2048, 256, 0, stream>>>(x, attn_w, (uint4*)xb, sxw, dxw);
  k_mbt2<<<NGROUP, 256, 0, stream>>>(relb, wtb, mbt);
  k_lgemm<<<V / 128, 256, 0, stream>>>(xb, mltb, bias, out0);
  k_edge<<<NSLAB, 512, 0, stream>>>(src, dst, et, sxw, dxw, rw,
                                    evals, packed, hist, drank, grank);
  k_gmeta<<<(NGROUP * 64 + 255) / 256, 256, 0, stream>>>(hist, cnt, rowpref);
  k_scan<<<1, 1024, 0, stream>>>(cnt, poffs);
  k_dscan1<<<NBLK_D, 1024, 0, stream>>>(packed, esum, dloc, dtot);
  k_dscan3<<<NBLK_D, 1024, 0, stream>>>(dloc, dtot, doffs);
  k_scatter<<<(E + 255) / 256, 256, 0, stream>>>(src, dst, et, evals, esum, enorm,
                                                 poffs, rowpref, doffs, drank, grank, edat);
  int Vs = V / ns;
  int partBase = 0;
  for (int s = 0; s < ns; ++s) {
    int lo = s * Vs, hi = (s == ns - 1) ? V : (s + 1) * Vs;
    int nb = (hi - lo + 15) / 16;
    k_msg3<<<NGROUP * 2, 256, 0, stream>>>(xb, mbt, cnt, poffs, edat,
                                           doffs, lo, hi, msgb);
    k_sum<<<nb, 256, 0, stream>>>(msgb, doffs, out0, part, lo, hi, partBase);
    partBase += nb;
  }
  int rpb = (partBase + 99) / 100;
  k_bn2a<<<100, 256, 0, stream>>>(part, part2, partBase, rpb);
  k_bn2b<<<1, 256, 0, stream>>>(part2, mrs);
  k_bn_norm<<<(V * D + 255) / 256, 256, 0, stream>>>(out0, mrs);
}